// Round 11
// baseline (113.196 us; speedup 1.0000x reference)
//
#include <hip/hip_runtime.h>
#include <hip/hip_bf16.h>

#define NS_TOT 2000
#define NA 1000
#define NI 5
#define NH 32
#define SHALF 1000                 // structs per block (two blocks per atom)
#define W2LD 40                    // sW2T leading dim (80B rows, bank-spread)
#define SC2 2.8853900817779268f    // 2*log2(e)

typedef __attribute__((ext_vector_type(2)))  float f32x2;
typedef __attribute__((ext_vector_type(8)))  short short8;   // 8 bf16 = 4 VGPR
typedef __attribute__((ext_vector_type(16))) float f32x16;   // MFMA 32x32 acc

struct f4pair  { f32x2 a, b; };
struct accpair { f32x2 p[8]; };

// R21: sigmoid-residual r = 1/(exp2(a)+1) from PRE-SCALED input a = 2log2e*y
// (scale folded into weight staging). Per pair: 2 exp + pk_add + paired-rcp
// (3 VALU + 1 TRANS). No input mul, no t-reconstruction, no clamps.
__device__ __forceinline__ f32x2 rfrom_pk(f32x2 A) {
    f32x2 E;
    E.x = __builtin_amdgcn_exp2f(A.x);
    E.y = __builtin_amdgcn_exp2f(A.y);
    const f32x2 D = E + 1.0f;
    const float rr = __builtin_amdgcn_rcpf(D.x * D.y);
    f32x2 r;
    r.x = rr * D.y;
    r.y = rr * D.x;
    return r;
}

__device__ __forceinline__ unsigned short f2bf_rne(float x) {
    unsigned u = __float_as_uint(x);
    unsigned r = u + 0x7FFFu + ((u >> 16) & 1u);
    return (unsigned short)(r >> 16);
}
__device__ __forceinline__ unsigned pack2(float a, float b) {
    __hip_bfloat162 p = __float22bfloat162_rn(make_float2(a, b));
    unsigned u; __builtin_memcpy(&u, &p, 4); return u;
}
// mid-layer: r-pair from pre-scaled acc values, packed to bf16x2.
// t = 1-2r is folded into the NEXT layer's weights (W2' = -2s*W2,
// b2' = s*(b2 + colsum W2)), so r is the MFMA operand directly.
__device__ __forceinline__ unsigned r2_pack(float a, float b) {
    f32x2 X = {a, b};
    f32x2 r = rfrom_pk(X);
    return pack2(r.x, r.y);
}

// R21 = R20 (exp-tanh via HW exp2; bench 119.7->113.2, the only live lever
// being instruction count) + three algebraic cuts:
//  1. s=2log2e folded into W1/b1 staging -> mid drops pk_mul per pair.
//  2. r packed directly; t=1-2r folded into W2'=-2s*W2, b2'=s*(b2+colsum W2)
//     -> mid drops pk_fma, epilogue drops pk_mul per pair.
//  3. dual-A BUILD: tile1 uses afl1b (weights on k=8..15 rows) so BOTH L1
//     MFMAs consume the same raw packed-g registers -- no permlane, no
//     masking (only half-0 words matter for tile0, half-1 for tile1).
// Host structure (pipelined source order, no fences, 2-ahead prefetch,
// hoisted b2acc/w3, cross-half epilogue swap) = R20 verbatim.
__global__ __attribute__((amdgpu_flat_work_group_size(256, 256),
                          amdgpu_waves_per_eu(3, 4)))
void mlp_mfma(
    const float* __restrict__ g,
    const float* __restrict__ W1, const float* __restrict__ b1,
    const float* __restrict__ W2, const float* __restrict__ b2,
    const float* __restrict__ W3, const float* __restrict__ b3,
    float* __restrict__ out)
{
    const int bid   = blockIdx.x;
    const int araw  = bid % NA;
    const int chunk = bid / NA;
    const int a = (araw >> 3) + 125 * (araw & 7);   // same-XCD atom swizzle
    const int t = threadIdx.x;
    const int lane = t & 63, wid = t >> 6;
    const int l31 = lane & 31, half = lane >> 5;

    const int sbase_blk = chunk * SHALF;
    const int send      = sbase_blk + SHALF;

    __shared__ __align__(16) unsigned short sW2T[NH * W2LD];  // (-2s*W2)^T bf16 [m][k]
    __shared__ __align__(16) unsigned short sW1T[NH * 8];     // [m]{s*W1[0..4][m],s*b1[m],0,0}
    __shared__ __align__(16) float sB2[NH];                   // s*(b2 + colsum W2)
    __shared__ __align__(16) float sW3[NH];

    for (int idx = t; idx < NH * NH; idx += 256) {
        const int i = idx >> 5, j = idx & 31;       // i = k row of W2, j = m col
        sW2T[j * W2LD + i] = f2bf_rne(W2[(size_t)a * NH * NH + idx] * (-2.0f * SC2));
    }
    if (t < NH) {
        const int m = t;
        float cs = 0.0f;                            // fp32 colsum of W2[:,m]
        #pragma unroll
        for (int k = 0; k < NH; ++k)
            cs += W2[(size_t)a * NH * NH + k * NH + m];
        sB2[m] = SC2 * (b2[a * NH + m] + cs);
        sW3[m] = W3[a * NH + m];
        #pragma unroll
        for (int i = 0; i < NI; ++i)
            sW1T[m * 8 + i] = f2bf_rne(W1[(size_t)a * NI * NH + i * NH + m] * SC2);
        sW1T[m * 8 + 5] = f2bf_rne(b1[a * NH + m] * SC2);
        sW1T[m * 8 + 6] = 0;
        sW1T[m * 8 + 7] = 0;
    }
    __syncthreads();

    // persistent fragments
    const short8 zero8 = {0,0,0,0,0,0,0,0};
    const short8 w1ld = __builtin_bit_cast(short8, *(const uint4*)(sW1T + l31 * 8));
    const short8 afl1a = half ? zero8 : w1ld;  // tile0: weights on k=0..7 rows
    const short8 afl1b = half ? w1ld : zero8;  // tile1: weights on k=8..15 rows
    const short8 af0 = __builtin_bit_cast(short8, *(const uint4*)(sW2T + l31 * W2LD + half * 8));
    const short8 af1 = __builtin_bit_cast(short8, *(const uint4*)(sW2T + l31 * W2LD + 16 + half * 8));
    const float4 b2q0 = ((const float4*)sB2)[0 + half];
    const float4 b2q1 = ((const float4*)sB2)[2 + half];
    const float4 b2q2 = ((const float4*)sB2)[4 + half];
    const float4 b2q3 = ((const float4*)sB2)[6 + half];
    const f4pair w3p0 = __builtin_bit_cast(f4pair, ((const float4*)sW3)[0 + half]);
    const f4pair w3p1 = __builtin_bit_cast(f4pair, ((const float4*)sW3)[2 + half]);
    const f4pair w3p2 = __builtin_bit_cast(f4pair, ((const float4*)sW3)[4 + half]);
    const f4pair w3p3 = __builtin_bit_cast(f4pair, ((const float4*)sW3)[6 + half]);
    // per-lane sum of this lane's 16 w3 values (for sum(t*w) folding)
    const f32x2 ws2 = w3p0.a + w3p0.b + w3p1.a + w3p1.b
                    + w3p2.a + w3p2.b + w3p3.a + w3p3.b;
    const float wsum = ws2.x + ws2.y;
    const float bias3 = b3[a];
    const f32x16 zacc = {0,0,0,0,0,0,0,0,0,0,0,0,0,0,0,0};
    const f32x16 b2acc = {b2q0.x, b2q0.y, b2q0.z, b2q0.w,
                          b2q1.x, b2q1.y, b2q1.z, b2q1.w,
                          b2q2.x, b2q2.y, b2q2.z, b2q2.w,
                          b2q3.x, b2q3.y, b2q3.z, b2q3.w};

    // dual-A g-frag build: same raw packed words feed both tiles (tile0
    // reads k=0..7 = half-0 lanes, tile1 reads k=8..15 = half-1 lanes;
    // the other half's words hit zeroed A rows -> garbage*0 = 0).
    #define BUILD_L1(AX0, AX1, AX2, AX3, AX4) { \
        const unsigned gp01 = pack2(AX0, AX1); \
        const unsigned gp23 = pack2(AX2, AX3); \
        const unsigned gp45 = pack2(AX4, 1.0f); \
        const short8 gbr = __builtin_bit_cast(short8, make_uint4(gp01, gp23, gp45, 0u)); \
        d0 = __builtin_amdgcn_mfma_f32_32x32x16_bf16(afl1a, gbr, zacc, 0, 0, 0); \
        d1 = __builtin_amdgcn_mfma_f32_32x32x16_bf16(afl1b, gbr, zacc, 0, 0, 0); }

    // prologue: g for it=0 (x*) and it=1 (y*); front-end of it=0.
    float x0g, x1g, x2g, x3g, x4g;
    float y0g, y1g, y2g, y3g, y4g;
    {
        const int s0 = sbase_blk + wid * 64 + lane;
        const float* gp = g + ((size_t)s0 * NA + a) * NI;
        x0g = gp[0]; x1g = gp[1]; x2g = gp[2]; x3g = gp[3]; x4g = gp[4];
        const int s1 = s0 + 256;                       // always < send for it=1
        const float* gq = g + ((size_t)s1 * NA + a) * NI;
        y0g = gq[0]; y1g = gq[1]; y2g = gq[2]; y3g = gq[3]; y4g = gq[4];
    }
    f32x16 d0, d1;
    BUILD_L1(x0g, x1g, x2g, x3g, x4g)

    #pragma unroll
    for (int it = 0; it < 4; ++it) {
        const int base = sbase_blk + it * 256 + wid * 64;
        const int s = base + lane;

        // ---- mid-layer: r-pack + permlane32_swap C->B (mapping verbatim) ----
        // C row of reg r = (r&3) + 8*(r>>2) + 4*half. swap(a,b).x = {a_lo,b_lo},
        // .y = {a_hi,b_hi}: exactly B-frag words (k = half*8 + 2w, 2w+1).
        short8 bk0_0, bk1_0, bk0_1, bk1_1;
        #define TILE_CONV(DD, BK0, BK1) { \
            const unsigned p0 = r2_pack(DD[0],  DD[1]); \
            const unsigned p1 = r2_pack(DD[2],  DD[3]); \
            const unsigned p2 = r2_pack(DD[4],  DD[5]); \
            const unsigned p3 = r2_pack(DD[6],  DD[7]); \
            const unsigned p4 = r2_pack(DD[8],  DD[9]); \
            const unsigned p5 = r2_pack(DD[10], DD[11]); \
            const unsigned p6 = r2_pack(DD[12], DD[13]); \
            const unsigned p7 = r2_pack(DD[14], DD[15]); \
            auto s02 = __builtin_amdgcn_permlane32_swap(p0, p2, false, false); \
            auto s13 = __builtin_amdgcn_permlane32_swap(p1, p3, false, false); \
            auto s46 = __builtin_amdgcn_permlane32_swap(p4, p6, false, false); \
            auto s57 = __builtin_amdgcn_permlane32_swap(p5, p7, false, false); \
            BK0 = __builtin_bit_cast(short8, make_uint4(s02[0], s13[0], s02[1], s13[1])); \
            BK1 = __builtin_bit_cast(short8, make_uint4(s46[0], s57[0], s46[1], s57[1])); }
        TILE_CONV(d0, bk0_0, bk1_0)
        TILE_CONV(d1, bk0_1, bk1_1)
        #undef TILE_CONV

        // ---- next-iter front-end (source-pipelined; scheduler may place) ----
        if (it < 3) {
            BUILD_L1(y0g, y1g, y2g, y3g, y4g)
        }

        // ---- layer 2 MFMA: acc = b2' + W2'*r = s*(W2*t + b2) ----
        f32x16 acc0 = __builtin_amdgcn_mfma_f32_32x32x16_bf16(af0, bk0_0, b2acc, 0, 0, 0);
        acc0 = __builtin_amdgcn_mfma_f32_32x32x16_bf16(af1, bk1_0, acc0, 0, 0, 0);
        f32x16 acc1 = __builtin_amdgcn_mfma_f32_32x32x16_bf16(af0, bk0_1, b2acc, 0, 0, 0);
        acc1 = __builtin_amdgcn_mfma_f32_32x32x16_bf16(af1, bk1_1, acc1, 0, 0, 0);

        // refill y* for it+2
        if (it < 2) {
            const int sn = s + 512;
            const int sln = (sn < send) ? sn : (send - 1);
            const float* gq = g + ((size_t)sln * NA + a) * NI;
            y0g = gq[0]; y1g = gq[1]; y2g = gq[2]; y3g = gq[3]; y4g = gq[4];
        }

        // ---- epilogue: folded dot  e = wsum - 2*sum(r*w)  (acc pre-scaled) ----
        const accpair ap0 = __builtin_bit_cast(accpair, acc0);
        f32x2 p0 = {0.f, 0.f};
        p0 += rfrom_pk(ap0.p[0]) * w3p0.a;  p0 += rfrom_pk(ap0.p[1]) * w3p0.b;
        p0 += rfrom_pk(ap0.p[2]) * w3p1.a;  p0 += rfrom_pk(ap0.p[3]) * w3p1.b;
        p0 += rfrom_pk(ap0.p[4]) * w3p2.a;  p0 += rfrom_pk(ap0.p[5]) * w3p2.b;
        p0 += rfrom_pk(ap0.p[6]) * w3p3.a;  p0 += rfrom_pk(ap0.p[7]) * w3p3.b;
        const float e0 = fmaf(-2.0f, p0.x + p0.y, wsum);
        const accpair ap1 = __builtin_bit_cast(accpair, acc1);
        f32x2 p1 = {0.f, 0.f};
        p1 += rfrom_pk(ap1.p[0]) * w3p0.a;  p1 += rfrom_pk(ap1.p[1]) * w3p0.b;
        p1 += rfrom_pk(ap1.p[2]) * w3p1.a;  p1 += rfrom_pk(ap1.p[3]) * w3p1.b;
        p1 += rfrom_pk(ap1.p[4]) * w3p2.a;  p1 += rfrom_pk(ap1.p[5]) * w3p2.b;
        p1 += rfrom_pk(ap1.p[6]) * w3p3.a;  p1 += rfrom_pk(ap1.p[7]) * w3p3.b;
        const float e1 = fmaf(-2.0f, p1.x + p1.y, wsum);
        // One swap fuses both cross-half reductions; every lane stores its
        // own struct: half0 lane l -> e0 sum (struct base+l), half1 -> e1.
        auto es = __builtin_amdgcn_permlane32_swap(__float_as_uint(e0),
                                                   __float_as_uint(e1),
                                                   false, false);
        const float etot = __uint_as_float(es[0]) + __uint_as_float(es[1]);
        if (s < send) out[(size_t)s * NA + a] = etot + bias3;
    }
    #undef BUILD_L1
}

extern "C" void kernel_launch(void* const* d_in, const int* in_sizes, int n_in,
                              void* d_out, int out_size, void* d_ws, size_t ws_size,
                              hipStream_t stream) {
    const float* g  = (const float*)d_in[0];
    const float* W1 = (const float*)d_in[1];
    const float* b1 = (const float*)d_in[2];
    const float* W2 = (const float*)d_in[3];
    const float* b2 = (const float*)d_in[4];
    const float* W3 = (const float*)d_in[5];
    const float* b3 = (const float*)d_in[6];
    float* out = (float*)d_out;
    mlp_mfma<<<dim3(NA * 2), dim3(256), 0, stream>>>(g, W1, b1, W2, b2, W3, b3, out);
}